// Round 6
// baseline (281.763 us; speedup 1.0000x reference)
//
#include <hip/hip_runtime.h>
#include <hip/hip_bf16.h>
#include <hip/hip_fp16.h>

#define N_NODES  50000
#define N_EDGES  800000
#define D        128
#define N_GRAPHS 64
#define CAP      64          // bucket capacity; in-deg ~ Poisson(16), P(>=64) ~ 1e-19
#define EW_SCALE 1048576.0f  // 2^20 fixed-point for packed weighted-degree
#define POOL_SPLIT 8

// ---------------------------------------------------------------------------
// init: packed (count|degsum) = 0, pooled = 0
// ---------------------------------------------------------------------------
__global__ void init_kernel(unsigned long long* __restrict__ packed,
                            float* __restrict__ pooled) {
    int i = blockIdx.x * 256 + threadIdx.x;
    if (i < N_NODES) packed[i] = 0ULL;
    if (i < N_GRAPHS * D) pooled[i] = 0.0f;
}

// ---------------------------------------------------------------------------
// fill: 4 edges/thread for atomic-latency pipelining. ONE returning 64-bit
// atomic per edge -> slot (hi bits) + fixed-point weighted degree (lo bits).
// bucket[c*64+pos] = (src_as_float, ew). Loads are int4/float4 coalesced.
// ---------------------------------------------------------------------------
__global__ __launch_bounds__(256) void fill_kernel(const int* __restrict__ ei,
                                                   const float* __restrict__ ew,
                                                   unsigned long long* __restrict__ packed,
                                                   float2* __restrict__ bucket) {
    int e0 = (blockIdx.x * 256 + threadIdx.x) * 4;
    if (e0 >= N_EDGES) return;                 // N_EDGES % 4 == 0, no partial tail
    int4   rs = *(const int4*)(ei + e0);
    int4   cs = *(const int4*)(ei + N_EDGES + e0);
    float4 wv = *(const float4*)(ew + e0);

    unsigned long long a0 = (1ULL << 40) | (unsigned long long)(unsigned)(wv.x * EW_SCALE + 0.5f);
    unsigned long long a1 = (1ULL << 40) | (unsigned long long)(unsigned)(wv.y * EW_SCALE + 0.5f);
    unsigned long long a2 = (1ULL << 40) | (unsigned long long)(unsigned)(wv.z * EW_SCALE + 0.5f);
    unsigned long long a3 = (1ULL << 40) | (unsigned long long)(unsigned)(wv.w * EW_SCALE + 0.5f);

    unsigned long long o0 = atomicAdd(&packed[cs.x], a0);
    unsigned long long o1 = atomicAdd(&packed[cs.y], a1);
    unsigned long long o2 = atomicAdd(&packed[cs.z], a2);
    unsigned long long o3 = atomicAdd(&packed[cs.w], a3);

    unsigned p0 = (unsigned)(o0 >> 40);
    unsigned p1 = (unsigned)(o1 >> 40);
    unsigned p2 = (unsigned)(o2 >> 40);
    unsigned p3 = (unsigned)(o3 >> 40);
    if (p0 < CAP) bucket[(size_t)cs.x * CAP + p0] = make_float2(__int_as_float(rs.x), wv.x);
    if (p1 < CAP) bucket[(size_t)cs.y * CAP + p1] = make_float2(__int_as_float(rs.y), wv.y);
    if (p2 < CAP) bucket[(size_t)cs.z * CAP + p2] = make_float2(__int_as_float(rs.z), wv.z);
    if (p3 < CAP) bucket[(size_t)cs.w * CAP + p3] = make_float2(__int_as_float(rs.w), wv.w);
}

// unpack cnt/dinv + graph starts from sorted batch (merged kernel)
__global__ void dinv_gstart_kernel(const unsigned long long* __restrict__ packed,
                                   int* __restrict__ cnt, float* __restrict__ dinv,
                                   const int* __restrict__ batch, int* __restrict__ gstart) {
    int i = blockIdx.x * 256 + threadIdx.x;
    if (i >= N_NODES) return;
    unsigned long long p = packed[i];
    int c = (int)(p >> 40);
    cnt[i] = c < CAP ? c : CAP;
    float deg = 1.0f + (float)(p & 0xFFFFFFFFFFULL) * (1.0f / EW_SCALE);
    dinv[i] = rsqrtf(deg);

    int a = batch[i];
    if (i == 0) {
        for (int g = 0; g <= a; g++) gstart[g] = 0;
    } else {
        int pg = batch[i - 1];
        for (int g = pg + 1; g <= a; g++) gstart[g] = i;
    }
    if (i == N_NODES - 1) {
        for (int g = a + 1; g <= N_GRAPHS; g++) gstart[g] = N_NODES;
    }
}

// fold dinv[src] into bucket vals once (used by BOTH agg layers).
__global__ void prep_kernel(const int* __restrict__ cnt, const float* __restrict__ dinv,
                            float2* __restrict__ bucket) {
    int idx = blockIdx.x * 256 + threadIdx.x;   // node*64 + slot, grid exact
    int node = idx >> 6;
    int slot = idx & 63;
    if (slot < cnt[node]) {
        float2 e = bucket[idx];
        bucket[idx].y = e.y * dinv[__float_as_int(e.x)];
    }
}

// ---------------------------------------------------------------------------
// GEMM: Y[n,128] = X[n,128] @ W[128,128], fp16 output (packed 16B stores).
// ---------------------------------------------------------------------------
__global__ __launch_bounds__(256) void gemm128h(const float* __restrict__ X,
                                                const float* __restrict__ W,
                                                __half* __restrict__ Yh, int nrows) {
    __shared__ float XT[64 * 128];  // XT[k][r]
    __shared__ float Ws[64 * 128];  // Ws[k][c]
    const int tid  = threadIdx.x;
    const int row0 = blockIdx.x * 128;
    const int tr = tid >> 4, tc = tid & 15;

    float acc[8][8] = {};

    for (int kt = 0; kt < 2; kt++) {
        const int kbase = kt * 64;
        {
            const float4* src = (const float4*)(W + kbase * 128);
            float4* dst = (float4*)Ws;
            for (int i = tid; i < 2048; i += 256) dst[i] = src[i];
        }
        {
            int r  = tid >> 1;
            int rr = row0 + r; if (rr >= nrows) rr = nrows - 1;
            int k0 = (tid & 1) * 32;
            const float4* src = (const float4*)(X + (size_t)rr * 128 + kbase + k0);
#pragma unroll
            for (int i = 0; i < 8; i++) {
                float4 v = src[i];
                int k = k0 + i * 4;
                XT[(k + 0) * 128 + r] = v.x;
                XT[(k + 1) * 128 + r] = v.y;
                XT[(k + 2) * 128 + r] = v.z;
                XT[(k + 3) * 128 + r] = v.w;
            }
        }
        __syncthreads();
#pragma unroll 4
        for (int k = 0; k < 64; k++) {
            float xs[8], ws[8];
            *(float4*)&xs[0] = *(const float4*)(XT + k * 128 + tr * 8);
            *(float4*)&xs[4] = *(const float4*)(XT + k * 128 + tr * 8 + 4);
            *(float4*)&ws[0] = *(const float4*)(Ws + k * 128 + tc * 8);
            *(float4*)&ws[4] = *(const float4*)(Ws + k * 128 + tc * 8 + 4);
#pragma unroll
            for (int i = 0; i < 8; i++)
#pragma unroll
                for (int j = 0; j < 8; j++)
                    acc[i][j] += xs[i] * ws[j];
        }
        __syncthreads();
    }
#pragma unroll
    for (int i = 0; i < 8; i++) {
        int r = row0 + tr * 8 + i;
        if (r < nrows) {
            __half2 h0 = __floats2half2_rn(acc[i][0], acc[i][1]);
            __half2 h1 = __floats2half2_rn(acc[i][2], acc[i][3]);
            __half2 h2 = __floats2half2_rn(acc[i][4], acc[i][5]);
            __half2 h3 = __floats2half2_rn(acc[i][6], acc[i][7]);
            uint4 p;
            p.x = *(unsigned int*)&h0; p.y = *(unsigned int*)&h1;
            p.z = *(unsigned int*)&h2; p.w = *(unsigned int*)&h3;
            *(uint4*)(Yh + (size_t)r * 128 + tc * 8) = p;
        }
    }
}

// ---------------------------------------------------------------------------
// Bucket aggregation (fp16 gather payload), fused self-loop + bias + ReLU.
// ---------------------------------------------------------------------------
__global__ __launch_bounds__(256) void agg_bucket_kernel(const __half* __restrict__ xwh,
                                                         const int* __restrict__ cnt,
                                                         const float2* __restrict__ bucket,
                                                         const float* __restrict__ dinv,
                                                         const float* __restrict__ bias,
                                                         float* __restrict__ out) {
    int node = blockIdx.x * 4 + (threadIdx.x >> 6);   // grid covers exactly N_NODES
    int lane = threadIdx.x & 63;
    const unsigned int* xh = (const unsigned int*)xwh;

    float dv = dinv[node];
    int n = cnt[node];

    float srcf = 0.0f, val = 0.0f;
    if (lane < n) {
        float2 eh = bucket[(size_t)node * CAP + lane];
        srcf = eh.x;
        val  = eh.y;                  // already ew*dinv[src]
    }

    unsigned int su = xh[(size_t)node * 64 + lane];
    float2 xs = __half22float2(*(__half2*)&su);
    float accx = dv * xs.x;
    float accy = dv * xs.y;

    int i = 0;
    for (; i + 3 < n; i += 4) {
        int   r0 = __float_as_int(__shfl(srcf, i));
        int   r1 = __float_as_int(__shfl(srcf, i + 1));
        int   r2 = __float_as_int(__shfl(srcf, i + 2));
        int   r3 = __float_as_int(__shfl(srcf, i + 3));
        float v0 = __shfl(val, i);
        float v1 = __shfl(val, i + 1);
        float v2 = __shfl(val, i + 2);
        float v3 = __shfl(val, i + 3);
        unsigned int m0 = xh[(size_t)r0 * 64 + lane];
        unsigned int m1 = xh[(size_t)r1 * 64 + lane];
        unsigned int m2 = xh[(size_t)r2 * 64 + lane];
        unsigned int m3 = xh[(size_t)r3 * 64 + lane];
        float2 f0 = __half22float2(*(__half2*)&m0);
        float2 f1 = __half22float2(*(__half2*)&m1);
        float2 f2 = __half22float2(*(__half2*)&m2);
        float2 f3 = __half22float2(*(__half2*)&m3);
        accx += v0 * f0.x + v1 * f1.x + v2 * f2.x + v3 * f3.x;
        accy += v0 * f0.y + v1 * f1.y + v2 * f2.y + v3 * f3.y;
    }
    for (; i < n; i++) {
        int   r0 = __float_as_int(__shfl(srcf, i));
        float v0 = __shfl(val, i);
        unsigned int m0 = xh[(size_t)r0 * 64 + lane];
        float2 f0 = __half22float2(*(__half2*)&m0);
        accx += v0 * f0.x;
        accy += v0 * f0.y;
    }

    float2 b = ((const float2*)bias)[lane];
    float2 o;
    o.x = fmaxf(dv * accx + b.x, 0.0f);
    o.y = fmaxf(dv * accy + b.y, 0.0f);
    ((float2*)out)[(size_t)node * 64 + lane] = o;
}

// ---------------------------------------------------------------------------
// Pool: grid = graph x slice; unroll-4 ILP; LDS reduce; 128 atomics/block.
// ---------------------------------------------------------------------------
__global__ __launch_bounds__(256) void pool_kernel(const float* __restrict__ h,
                                                   const int* __restrict__ gstart,
                                                   float* __restrict__ pooled) {
    int g = blockIdx.x >> 3;
    int s = blockIdx.x & (POOL_SPLIT - 1);
    int a = gstart[g], b = gstart[g + 1];
    int len = b - a;
    int lo = a + (int)((long long)len * s / POOL_SPLIT);
    int hi = a + (int)((long long)len * (s + 1) / POOL_SPLIT);

    int d2 = threadIdx.x & 63;
    int nl = threadIdx.x >> 6;
    const float2* h2 = (const float2*)h;

    float accx = 0.0f, accy = 0.0f;
    int n = lo + nl;
    for (; n + 12 < hi; n += 16) {
        float2 v0 = h2[(size_t)n * 64 + d2];
        float2 v1 = h2[(size_t)(n + 4) * 64 + d2];
        float2 v2 = h2[(size_t)(n + 8) * 64 + d2];
        float2 v3 = h2[(size_t)(n + 12) * 64 + d2];
        accx += (v0.x + v1.x) + (v2.x + v3.x);
        accy += (v0.y + v1.y) + (v2.y + v3.y);
    }
    for (; n < hi; n += 4) {
        float2 v = h2[(size_t)n * 64 + d2];
        accx += v.x; accy += v.y;
    }

    __shared__ float red[4][128];
    red[nl][d2 * 2]     = accx;
    red[nl][d2 * 2 + 1] = accy;
    __syncthreads();
    if (threadIdx.x < 128) {
        float v = red[0][threadIdx.x] + red[1][threadIdx.x]
                + red[2][threadIdx.x] + red[3][threadIdx.x];
        atomicAdd(&pooled[(size_t)g * 128 + threadIdx.x], v);
    }
}

__global__ __launch_bounds__(64) void final_kernel(const float* __restrict__ pooled,
                                                   const int* __restrict__ gstart,
                                                   const float* __restrict__ Wh,
                                                   const float* __restrict__ bh,
                                                   float* __restrict__ out) {
    int g = blockIdx.x;
    int t = threadIdx.x;
    float v = pooled[(size_t)g * 128 + t] * Wh[t]
            + pooled[(size_t)g * 128 + 64 + t] * Wh[64 + t];
#pragma unroll
    for (int off = 32; off > 0; off >>= 1) v += __shfl_down(v, off, 64);
    if (t == 0) {
        float cntf = (float)(gstart[g + 1] - gstart[g]);
        out[g] = v / fmaxf(cntf, 1.0f) + bh[0];
    }
}

// ---------------------------------------------------------------------------
extern "C" void kernel_launch(void* const* d_in, const int* in_sizes, int n_in,
                              void* d_out, int out_size, void* d_ws, size_t ws_size,
                              hipStream_t stream) {
    const float* x   = (const float*)d_in[0];
    const float* ew  = (const float*)d_in[1];
    const float* W1  = (const float*)d_in[2];
    const float* b1  = (const float*)d_in[3];
    const float* W2  = (const float*)d_in[4];
    const float* b2  = (const float*)d_in[5];
    const float* Wh  = (const float*)d_in[6];
    const float* bh  = (const float*)d_in[7];
    const int*   ei  = (const int*)d_in[8];
    const int*   bat = (const int*)d_in[9];
    float* out = (float*)d_out;

    char* ws = (char*)d_ws;
    float*  bufB   = (float*)ws;                          ws += (size_t)N_NODES * D * 4;
    __half* bufAh  = (__half*)ws;                         ws += (size_t)N_NODES * D * 2;
    float2* bucket = (float2*)ws;                         ws += (size_t)N_NODES * CAP * 8;
    unsigned long long* packed = (unsigned long long*)ws; ws += (size_t)N_NODES * 8;
    float*  dinv   = (float*)ws;                          ws += (size_t)N_NODES * 4;
    int*    cnt    = (int*)ws;                            ws += (size_t)N_NODES * 4;
    int*    gstart = (int*)ws;                            ws += (N_GRAPHS + 1) * 4;
    float*  pooled = (float*)ws;                          ws += (size_t)N_GRAPHS * D * 4;

    const int nb_nodes = (N_NODES + 255) / 256;       // 196
    const int nb_fill  = (N_EDGES / 4 + 255) / 256;   // 782
    const int nb_gemm  = (N_NODES + 127) / 128;       // 391
    const int nb_agg   = N_NODES / 4;                 // 12500 (exact)
    const int nb_prep  = N_NODES * CAP / 256;         // 12500 (exact)
    const int nb_pool  = N_GRAPHS * POOL_SPLIT;       // 512

    // --- build ---
    init_kernel<<<nb_nodes, 256, 0, stream>>>(packed, pooled);
    fill_kernel<<<nb_fill, 256, 0, stream>>>(ei, ew, packed, bucket);
    dinv_gstart_kernel<<<nb_nodes, 256, 0, stream>>>(packed, cnt, dinv, bat, gstart);
    prep_kernel<<<nb_prep, 256, 0, stream>>>(cnt, dinv, bucket);

    // --- layer 1 ---
    gemm128h<<<nb_gemm, 256, 0, stream>>>(x, W1, bufAh, N_NODES);
    agg_bucket_kernel<<<nb_agg, 256, 0, stream>>>(bufAh, cnt, bucket, dinv, b1, bufB);

    // --- layer 2 ---
    gemm128h<<<nb_gemm, 256, 0, stream>>>(bufB, W2, bufAh, N_NODES);
    agg_bucket_kernel<<<nb_agg, 256, 0, stream>>>(bufAh, cnt, bucket, dinv, b2, bufB);

    // --- pool + head ---
    pool_kernel<<<nb_pool, 256, 0, stream>>>(bufB, gstart, pooled);
    final_kernel<<<N_GRAPHS, 64, 0, stream>>>(pooled, gstart, Wh, bh, out);
}

// Round 7
// 279.646 us; speedup vs baseline: 1.0076x; 1.0076x over previous
//
#include <hip/hip_runtime.h>
#include <hip/hip_bf16.h>
#include <hip/hip_fp16.h>

#define N_NODES  50000
#define N_EDGES  800000
#define D        128
#define N_GRAPHS 64
#define CAP      64          // bucket capacity; in-deg ~ Poisson(16), P(>=64) ~ 1e-19
#define EW_SCALE 1048576.0f  // 2^20 fixed-point for packed weighted-degree
#define POOL_SPLIT 8
#define PPAD     16          // packed-counter stride in u64 units: 128B/counter (line-pad)

// ---------------------------------------------------------------------------
// init: packed (count|degsum) = 0 (one counter per 128B line), pooled = 0
// ---------------------------------------------------------------------------
__global__ void init_kernel(unsigned long long* __restrict__ packed,
                            float* __restrict__ pooled) {
    int i = blockIdx.x * 256 + threadIdx.x;
    if (i < N_NODES) packed[(size_t)i * PPAD] = 0ULL;
    if (i < N_GRAPHS * D) pooled[i] = 0.0f;
}

// ---------------------------------------------------------------------------
// fill: 1 edge/thread (max wave count). ONE returning 64-bit atomic per edge
// -> slot (hi bits) + fixed-point weighted degree (lo bits). Counters padded
// to 128B each so TCC same-line RMW hazards vanish.
// ---------------------------------------------------------------------------
__global__ __launch_bounds__(256) void fill_kernel(const int* __restrict__ ei,
                                                   const float* __restrict__ ew,
                                                   unsigned long long* __restrict__ packed,
                                                   float2* __restrict__ bucket) {
    int e = blockIdx.x * 256 + threadIdx.x;
    if (e >= N_EDGES) return;
    int r = ei[e];
    int c = ei[N_EDGES + e];
    float w = ew[e];
    unsigned long long add = (1ULL << 40) | (unsigned long long)(unsigned)(w * EW_SCALE + 0.5f);
    unsigned long long old = atomicAdd(&packed[(size_t)c * PPAD], add);
    unsigned pos = (unsigned)(old >> 40);
    if (pos < CAP)
        bucket[(size_t)c * CAP + pos] = make_float2(__int_as_float(r), w);
}

// unpack cnt/dinv + graph starts from sorted batch (merged kernel)
__global__ void dinv_gstart_kernel(const unsigned long long* __restrict__ packed,
                                   int* __restrict__ cnt, float* __restrict__ dinv,
                                   const int* __restrict__ batch, int* __restrict__ gstart) {
    int i = blockIdx.x * 256 + threadIdx.x;
    if (i >= N_NODES) return;
    unsigned long long p = packed[(size_t)i * PPAD];
    int c = (int)(p >> 40);
    cnt[i] = c < CAP ? c : CAP;
    float deg = 1.0f + (float)(p & 0xFFFFFFFFFFULL) * (1.0f / EW_SCALE);
    dinv[i] = rsqrtf(deg);

    int a = batch[i];
    if (i == 0) {
        for (int g = 0; g <= a; g++) gstart[g] = 0;
    } else {
        int pg = batch[i - 1];
        for (int g = pg + 1; g <= a; g++) gstart[g] = i;
    }
    if (i == N_NODES - 1) {
        for (int g = a + 1; g <= N_GRAPHS; g++) gstart[g] = N_NODES;
    }
}

// fold dinv[src] into bucket vals once (used by BOTH agg layers).
__global__ void prep_kernel(const int* __restrict__ cnt, const float* __restrict__ dinv,
                            float2* __restrict__ bucket) {
    int idx = blockIdx.x * 256 + threadIdx.x;   // node*64 + slot, grid exact
    int node = idx >> 6;
    int slot = idx & 63;
    if (slot < cnt[node]) {
        float2 e = bucket[idx];
        bucket[idx].y = e.y * dinv[__float_as_int(e.x)];
    }
}

// ---------------------------------------------------------------------------
// GEMM: Y[n,128] = X[n,128] @ W[128,128], fp16 output (packed 16B stores).
// ---------------------------------------------------------------------------
__global__ __launch_bounds__(256) void gemm128h(const float* __restrict__ X,
                                                const float* __restrict__ W,
                                                __half* __restrict__ Yh, int nrows) {
    __shared__ float XT[64 * 128];  // XT[k][r]
    __shared__ float Ws[64 * 128];  // Ws[k][c]
    const int tid  = threadIdx.x;
    const int row0 = blockIdx.x * 128;
    const int tr = tid >> 4, tc = tid & 15;

    float acc[8][8] = {};

    for (int kt = 0; kt < 2; kt++) {
        const int kbase = kt * 64;
        {
            const float4* src = (const float4*)(W + kbase * 128);
            float4* dst = (float4*)Ws;
            for (int i = tid; i < 2048; i += 256) dst[i] = src[i];
        }
        {
            int r  = tid >> 1;
            int rr = row0 + r; if (rr >= nrows) rr = nrows - 1;
            int k0 = (tid & 1) * 32;
            const float4* src = (const float4*)(X + (size_t)rr * 128 + kbase + k0);
#pragma unroll
            for (int i = 0; i < 8; i++) {
                float4 v = src[i];
                int k = k0 + i * 4;
                XT[(k + 0) * 128 + r] = v.x;
                XT[(k + 1) * 128 + r] = v.y;
                XT[(k + 2) * 128 + r] = v.z;
                XT[(k + 3) * 128 + r] = v.w;
            }
        }
        __syncthreads();
#pragma unroll 4
        for (int k = 0; k < 64; k++) {
            float xs[8], ws[8];
            *(float4*)&xs[0] = *(const float4*)(XT + k * 128 + tr * 8);
            *(float4*)&xs[4] = *(const float4*)(XT + k * 128 + tr * 8 + 4);
            *(float4*)&ws[0] = *(const float4*)(Ws + k * 128 + tc * 8);
            *(float4*)&ws[4] = *(const float4*)(Ws + k * 128 + tc * 8 + 4);
#pragma unroll
            for (int i = 0; i < 8; i++)
#pragma unroll
                for (int j = 0; j < 8; j++)
                    acc[i][j] += xs[i] * ws[j];
        }
        __syncthreads();
    }
#pragma unroll
    for (int i = 0; i < 8; i++) {
        int r = row0 + tr * 8 + i;
        if (r < nrows) {
            __half2 h0 = __floats2half2_rn(acc[i][0], acc[i][1]);
            __half2 h1 = __floats2half2_rn(acc[i][2], acc[i][3]);
            __half2 h2 = __floats2half2_rn(acc[i][4], acc[i][5]);
            __half2 h3 = __floats2half2_rn(acc[i][6], acc[i][7]);
            uint4 p;
            p.x = *(unsigned int*)&h0; p.y = *(unsigned int*)&h1;
            p.z = *(unsigned int*)&h2; p.w = *(unsigned int*)&h3;
            *(uint4*)(Yh + (size_t)r * 128 + tc * 8) = p;
        }
    }
}

// ---------------------------------------------------------------------------
// Bucket aggregation (fp16 gather payload), fused self-loop + bias + ReLU.
// ---------------------------------------------------------------------------
__global__ __launch_bounds__(256) void agg_bucket_kernel(const __half* __restrict__ xwh,
                                                         const int* __restrict__ cnt,
                                                         const float2* __restrict__ bucket,
                                                         const float* __restrict__ dinv,
                                                         const float* __restrict__ bias,
                                                         float* __restrict__ out) {
    int node = blockIdx.x * 4 + (threadIdx.x >> 6);   // grid covers exactly N_NODES
    int lane = threadIdx.x & 63;
    const unsigned int* xh = (const unsigned int*)xwh;

    float dv = dinv[node];
    int n = cnt[node];

    float srcf = 0.0f, val = 0.0f;
    if (lane < n) {
        float2 eh = bucket[(size_t)node * CAP + lane];
        srcf = eh.x;
        val  = eh.y;                  // already ew*dinv[src]
    }

    unsigned int su = xh[(size_t)node * 64 + lane];
    float2 xs = __half22float2(*(__half2*)&su);
    float accx = dv * xs.x;
    float accy = dv * xs.y;

    int i = 0;
    for (; i + 3 < n; i += 4) {
        int   r0 = __float_as_int(__shfl(srcf, i));
        int   r1 = __float_as_int(__shfl(srcf, i + 1));
        int   r2 = __float_as_int(__shfl(srcf, i + 2));
        int   r3 = __float_as_int(__shfl(srcf, i + 3));
        float v0 = __shfl(val, i);
        float v1 = __shfl(val, i + 1);
        float v2 = __shfl(val, i + 2);
        float v3 = __shfl(val, i + 3);
        unsigned int m0 = xh[(size_t)r0 * 64 + lane];
        unsigned int m1 = xh[(size_t)r1 * 64 + lane];
        unsigned int m2 = xh[(size_t)r2 * 64 + lane];
        unsigned int m3 = xh[(size_t)r3 * 64 + lane];
        float2 f0 = __half22float2(*(__half2*)&m0);
        float2 f1 = __half22float2(*(__half2*)&m1);
        float2 f2 = __half22float2(*(__half2*)&m2);
        float2 f3 = __half22float2(*(__half2*)&m3);
        accx += v0 * f0.x + v1 * f1.x + v2 * f2.x + v3 * f3.x;
        accy += v0 * f0.y + v1 * f1.y + v2 * f2.y + v3 * f3.y;
    }
    for (; i < n; i++) {
        int   r0 = __float_as_int(__shfl(srcf, i));
        float v0 = __shfl(val, i);
        unsigned int m0 = xh[(size_t)r0 * 64 + lane];
        float2 f0 = __half22float2(*(__half2*)&m0);
        accx += v0 * f0.x;
        accy += v0 * f0.y;
    }

    float2 b = ((const float2*)bias)[lane];
    float2 o;
    o.x = fmaxf(dv * accx + b.x, 0.0f);
    o.y = fmaxf(dv * accy + b.y, 0.0f);
    ((float2*)out)[(size_t)node * 64 + lane] = o;
}

// ---------------------------------------------------------------------------
// Pool: grid = graph x slice; unroll-4 ILP; LDS reduce; 128 atomics/block.
// ---------------------------------------------------------------------------
__global__ __launch_bounds__(256) void pool_kernel(const float* __restrict__ h,
                                                   const int* __restrict__ gstart,
                                                   float* __restrict__ pooled) {
    int g = blockIdx.x >> 3;
    int s = blockIdx.x & (POOL_SPLIT - 1);
    int a = gstart[g], b = gstart[g + 1];
    int len = b - a;
    int lo = a + (int)((long long)len * s / POOL_SPLIT);
    int hi = a + (int)((long long)len * (s + 1) / POOL_SPLIT);

    int d2 = threadIdx.x & 63;
    int nl = threadIdx.x >> 6;
    const float2* h2 = (const float2*)h;

    float accx = 0.0f, accy = 0.0f;
    int n = lo + nl;
    for (; n + 12 < hi; n += 16) {
        float2 v0 = h2[(size_t)n * 64 + d2];
        float2 v1 = h2[(size_t)(n + 4) * 64 + d2];
        float2 v2 = h2[(size_t)(n + 8) * 64 + d2];
        float2 v3 = h2[(size_t)(n + 12) * 64 + d2];
        accx += (v0.x + v1.x) + (v2.x + v3.x);
        accy += (v0.y + v1.y) + (v2.y + v3.y);
    }
    for (; n < hi; n += 4) {
        float2 v = h2[(size_t)n * 64 + d2];
        accx += v.x; accy += v.y;
    }

    __shared__ float red[4][128];
    red[nl][d2 * 2]     = accx;
    red[nl][d2 * 2 + 1] = accy;
    __syncthreads();
    if (threadIdx.x < 128) {
        float v = red[0][threadIdx.x] + red[1][threadIdx.x]
                + red[2][threadIdx.x] + red[3][threadIdx.x];
        atomicAdd(&pooled[(size_t)g * 128 + threadIdx.x], v);
    }
}

__global__ __launch_bounds__(64) void final_kernel(const float* __restrict__ pooled,
                                                   const int* __restrict__ gstart,
                                                   const float* __restrict__ Wh,
                                                   const float* __restrict__ bh,
                                                   float* __restrict__ out) {
    int g = blockIdx.x;
    int t = threadIdx.x;
    float v = pooled[(size_t)g * 128 + t] * Wh[t]
            + pooled[(size_t)g * 128 + 64 + t] * Wh[64 + t];
#pragma unroll
    for (int off = 32; off > 0; off >>= 1) v += __shfl_down(v, off, 64);
    if (t == 0) {
        float cntf = (float)(gstart[g + 1] - gstart[g]);
        out[g] = v / fmaxf(cntf, 1.0f) + bh[0];
    }
}

// ---------------------------------------------------------------------------
extern "C" void kernel_launch(void* const* d_in, const int* in_sizes, int n_in,
                              void* d_out, int out_size, void* d_ws, size_t ws_size,
                              hipStream_t stream) {
    const float* x   = (const float*)d_in[0];
    const float* ew  = (const float*)d_in[1];
    const float* W1  = (const float*)d_in[2];
    const float* b1  = (const float*)d_in[3];
    const float* W2  = (const float*)d_in[4];
    const float* b2  = (const float*)d_in[5];
    const float* Wh  = (const float*)d_in[6];
    const float* bh  = (const float*)d_in[7];
    const int*   ei  = (const int*)d_in[8];
    const int*   bat = (const int*)d_in[9];
    float* out = (float*)d_out;

    char* ws = (char*)d_ws;
    float*  bufB   = (float*)ws;                          ws += (size_t)N_NODES * D * 4;
    __half* bufAh  = (__half*)ws;                         ws += (size_t)N_NODES * D * 2;
    float2* bucket = (float2*)ws;                         ws += (size_t)N_NODES * CAP * 8;
    unsigned long long* packed = (unsigned long long*)ws; ws += (size_t)N_NODES * PPAD * 8;
    float*  dinv   = (float*)ws;                          ws += (size_t)N_NODES * 4;
    int*    cnt    = (int*)ws;                            ws += (size_t)N_NODES * 4;
    int*    gstart = (int*)ws;                            ws += (N_GRAPHS + 1) * 4;
    float*  pooled = (float*)ws;                          ws += (size_t)N_GRAPHS * D * 4;

    const int nb_nodes = (N_NODES + 255) / 256;       // 196
    const int nb_edges = (N_EDGES + 255) / 256;       // 3125
    const int nb_gemm  = (N_NODES + 127) / 128;       // 391
    const int nb_agg   = N_NODES / 4;                 // 12500 (exact)
    const int nb_prep  = N_NODES * CAP / 256;         // 12500 (exact)
    const int nb_pool  = N_GRAPHS * POOL_SPLIT;       // 512

    // --- build ---
    init_kernel<<<nb_nodes, 256, 0, stream>>>(packed, pooled);
    fill_kernel<<<nb_edges, 256, 0, stream>>>(ei, ew, packed, bucket);
    dinv_gstart_kernel<<<nb_nodes, 256, 0, stream>>>(packed, cnt, dinv, bat, gstart);
    prep_kernel<<<nb_prep, 256, 0, stream>>>(cnt, dinv, bucket);

    // --- layer 1 ---
    gemm128h<<<nb_gemm, 256, 0, stream>>>(x, W1, bufAh, N_NODES);
    agg_bucket_kernel<<<nb_agg, 256, 0, stream>>>(bufAh, cnt, bucket, dinv, b1, bufB);

    // --- layer 2 ---
    gemm128h<<<nb_gemm, 256, 0, stream>>>(bufB, W2, bufAh, N_NODES);
    agg_bucket_kernel<<<nb_agg, 256, 0, stream>>>(bufAh, cnt, bucket, dinv, b2, bufB);

    // --- pool + head ---
    pool_kernel<<<nb_pool, 256, 0, stream>>>(bufB, gstart, pooled);
    final_kernel<<<N_GRAPHS, 64, 0, stream>>>(pooled, gstart, Wh, bh, out);
}

// Round 8
// 254.450 us; speedup vs baseline: 1.1073x; 1.0990x over previous
//
#include <hip/hip_runtime.h>
#include <hip/hip_bf16.h>
#include <hip/hip_fp16.h>

#define N_NODES  50000
#define N_EDGES  800000
#define D        128
#define N_GRAPHS 64
#define CAP      64          // bucket capacity; in-deg ~ Poisson(16), P(>=64) ~ 1e-19
#define EW_SCALE 1048576.0f  // 2^20 fixed-point for packed weighted-degree
#define POOL_SPLIT 8
#define NB_GEMM1 391         // gemm blocks in the fused kernel (ceil(50000/128))
#define NB_FILL  3125        // fill blocks (800000/256)

__device__ __forceinline__ float2 h2f(unsigned int u) {
    __half2 h = *reinterpret_cast<__half2*>(&u);
    return __half22float2(h);
}
__device__ __forceinline__ unsigned int f2h(float a, float b) {
    __half2 h = __floats2half2_rn(a, b);
    return *reinterpret_cast<unsigned int*>(&h);
}

// ---------------------------------------------------------------------------
// FUSED: blocks [0,391) = gemm1 (fp32 x @ W1 -> fp16, unscaled);
//        blocks [391, 3516) = fill (1 edge/thread, packed returning atomic).
// fill is atomic-throughput-bound (~15G/s, occupancy-insensitive: r6/r7);
// gemm is VALU-bound -> co-scheduling gives ~max not sum.
// ---------------------------------------------------------------------------
__global__ __launch_bounds__(256) void fused_gemm1_fill(const float* __restrict__ X,
                                                        const float* __restrict__ W,
                                                        __half* __restrict__ Yh,
                                                        const int* __restrict__ ei,
                                                        const float* __restrict__ ew,
                                                        unsigned long long* __restrict__ packed,
                                                        float2* __restrict__ bucket) {
    __shared__ float XT[64 * 128];  // XT[k][r]
    __shared__ float Ws[64 * 128];  // Ws[k][c]

    if (blockIdx.x >= NB_GEMM1) {
        // ---- fill branch ----
        int e = (blockIdx.x - NB_GEMM1) * 256 + threadIdx.x;
        if (e >= N_EDGES) return;
        int r = ei[e];
        int c = ei[N_EDGES + e];
        float w = ew[e];
        unsigned long long add = (1ULL << 40) | (unsigned long long)(unsigned)(w * EW_SCALE + 0.5f);
        unsigned long long old = atomicAdd(&packed[c], add);
        unsigned pos = (unsigned)(old >> 40);
        if (pos < CAP)
            bucket[(size_t)c * CAP + pos] = make_float2(__int_as_float(r), w);
        return;
    }

    // ---- gemm branch: Y[n,128] = X[n,128] @ W[128,128], fp16 out ----
    const int tid  = threadIdx.x;
    const int row0 = blockIdx.x * 128;
    const int tr = tid >> 4, tc = tid & 15;
    float acc[8][8] = {};

    for (int kt = 0; kt < 2; kt++) {
        const int kbase = kt * 64;
        {
            const float4* src = (const float4*)(W + kbase * 128);
            float4* dst = (float4*)Ws;
            for (int i = tid; i < 2048; i += 256) dst[i] = src[i];
        }
        {
            int r  = tid >> 1;
            int rr = row0 + r; if (rr >= N_NODES) rr = N_NODES - 1;
            int k0 = (tid & 1) * 32;
            const float4* src = (const float4*)(X + (size_t)rr * 128 + kbase + k0);
#pragma unroll
            for (int i = 0; i < 8; i++) {
                float4 v = src[i];
                int k = k0 + i * 4;
                XT[(k + 0) * 128 + r] = v.x;
                XT[(k + 1) * 128 + r] = v.y;
                XT[(k + 2) * 128 + r] = v.z;
                XT[(k + 3) * 128 + r] = v.w;
            }
        }
        __syncthreads();
#pragma unroll 4
        for (int k = 0; k < 64; k++) {
            float xs[8], ws[8];
            *(float4*)&xs[0] = *(const float4*)(XT + k * 128 + tr * 8);
            *(float4*)&xs[4] = *(const float4*)(XT + k * 128 + tr * 8 + 4);
            *(float4*)&ws[0] = *(const float4*)(Ws + k * 128 + tc * 8);
            *(float4*)&ws[4] = *(const float4*)(Ws + k * 128 + tc * 8 + 4);
#pragma unroll
            for (int i = 0; i < 8; i++)
#pragma unroll
                for (int j = 0; j < 8; j++)
                    acc[i][j] += xs[i] * ws[j];
        }
        __syncthreads();
    }
#pragma unroll
    for (int i = 0; i < 8; i++) {
        int r = row0 + tr * 8 + i;
        if (r < N_NODES) {
            uint4 p;
            p.x = f2h(acc[i][0], acc[i][1]);
            p.y = f2h(acc[i][2], acc[i][3]);
            p.z = f2h(acc[i][4], acc[i][5]);
            p.w = f2h(acc[i][6], acc[i][7]);
            *(uint4*)(Yh + (size_t)r * 128 + tc * 8) = p;
        }
    }
}

// unpack cnt/dinv + graph starts from sorted batch (merged kernel)
__global__ void dinv_gstart_kernel(const unsigned long long* __restrict__ packed,
                                   int* __restrict__ cnt, float* __restrict__ dinv,
                                   const int* __restrict__ batch, int* __restrict__ gstart) {
    int i = blockIdx.x * 256 + threadIdx.x;
    if (i >= N_NODES) return;
    unsigned long long p = packed[i];
    int c = (int)(p >> 40);
    cnt[i] = c < CAP ? c : CAP;
    float deg = 1.0f + (float)(p & 0xFFFFFFFFFFULL) * (1.0f / EW_SCALE);
    dinv[i] = rsqrtf(deg);

    int a = batch[i];
    if (i == 0) {
        for (int g = 0; g <= a; g++) gstart[g] = 0;
    } else {
        int pg = batch[i - 1];
        for (int g = pg + 1; g <= a; g++) gstart[g] = i;
    }
    if (i == N_NODES - 1) {
        for (int g = a + 1; g <= N_GRAPHS; g++) gstart[g] = N_NODES;
    }
}

// x' = dinv[node] * x (fp16 in place, coalesced half2/thread)
__global__ __launch_bounds__(256) void scale_kernel(unsigned int* __restrict__ xh,
                                                    const float* __restrict__ dinv) {
    int idx = blockIdx.x * 256 + threadIdx.x;   // covers exactly N_NODES*64
    float dv = dinv[idx >> 6];
    float2 f = h2f(xh[idx]);
    xh[idx] = f2h(f.x * dv, f.y * dv);
}

// ---------------------------------------------------------------------------
// gemm2: Y = X(fp16) @ W(fp32), epilogue * dinv[row] -> fp16 (x2').
// ---------------------------------------------------------------------------
__global__ __launch_bounds__(256) void gemm128h2(const __half* __restrict__ Xh,
                                                 const float* __restrict__ W,
                                                 const float* __restrict__ dinv,
                                                 __half* __restrict__ Yh) {
    __shared__ float XT[64 * 128];  // XT[k][r]
    __shared__ float Ws[64 * 128];  // Ws[k][c]
    const int tid  = threadIdx.x;
    const int row0 = blockIdx.x * 128;
    const int tr = tid >> 4, tc = tid & 15;
    float acc[8][8] = {};

    for (int kt = 0; kt < 2; kt++) {
        const int kbase = kt * 64;
        {
            const float4* src = (const float4*)(W + kbase * 128);
            float4* dst = (float4*)Ws;
            for (int i = tid; i < 2048; i += 256) dst[i] = src[i];
        }
        {
            int r  = tid >> 1;
            int rr = row0 + r; if (rr >= N_NODES) rr = N_NODES - 1;
            int k0 = (tid & 1) * 32;
            const unsigned int* src = (const unsigned int*)(Xh + (size_t)rr * 128 + kbase + k0);
#pragma unroll
            for (int i = 0; i < 16; i++) {
                float2 f = h2f(src[i]);
                int k = k0 + i * 2;
                XT[(k + 0) * 128 + r] = f.x;
                XT[(k + 1) * 128 + r] = f.y;
            }
        }
        __syncthreads();
#pragma unroll 4
        for (int k = 0; k < 64; k++) {
            float xs[8], ws[8];
            *(float4*)&xs[0] = *(const float4*)(XT + k * 128 + tr * 8);
            *(float4*)&xs[4] = *(const float4*)(XT + k * 128 + tr * 8 + 4);
            *(float4*)&ws[0] = *(const float4*)(Ws + k * 128 + tc * 8);
            *(float4*)&ws[4] = *(const float4*)(Ws + k * 128 + tc * 8 + 4);
#pragma unroll
            for (int i = 0; i < 8; i++)
#pragma unroll
                for (int j = 0; j < 8; j++)
                    acc[i][j] += xs[i] * ws[j];
        }
        __syncthreads();
    }
#pragma unroll
    for (int i = 0; i < 8; i++) {
        int r = row0 + tr * 8 + i;
        if (r < N_NODES) {
            float s = dinv[r];
            uint4 p;
            p.x = f2h(acc[i][0] * s, acc[i][1] * s);
            p.y = f2h(acc[i][2] * s, acc[i][3] * s);
            p.z = f2h(acc[i][4] * s, acc[i][5] * s);
            p.w = f2h(acc[i][6] * s, acc[i][7] * s);
            *(uint4*)(Yh + (size_t)r * 128 + tc * 8) = p;
        }
    }
}

// ---------------------------------------------------------------------------
// Bucket aggregation on pre-scaled features x' (fp16 in, fp16 out):
//   out[c] = relu( dinv[c]*(x'[c] + sum ew_i * x'[src_i]) + b )
// One wave per node; headers broadcast via shfl; raw ew from bucket.
// ---------------------------------------------------------------------------
__global__ __launch_bounds__(256) void agg_bucket_kernel(const __half* __restrict__ xwh,
                                                         const int* __restrict__ cnt,
                                                         const float2* __restrict__ bucket,
                                                         const float* __restrict__ dinv,
                                                         const float* __restrict__ bias,
                                                         __half* __restrict__ outh) {
    int node = blockIdx.x * 4 + (threadIdx.x >> 6);   // grid covers exactly N_NODES
    int lane = threadIdx.x & 63;
    const unsigned int* xh = (const unsigned int*)xwh;

    float dv = dinv[node];
    int n = cnt[node];

    float srcf = 0.0f, val = 0.0f;
    if (lane < n) {
        float2 eh = bucket[(size_t)node * CAP + lane];
        srcf = eh.x;
        val  = eh.y;                  // raw ew (features carry the dinv factors)
    }

    float2 xs = h2f(xh[(size_t)node * 64 + lane]);
    float accx = xs.x;
    float accy = xs.y;

    int i = 0;
    for (; i + 3 < n; i += 4) {
        int   r0 = __float_as_int(__shfl(srcf, i));
        int   r1 = __float_as_int(__shfl(srcf, i + 1));
        int   r2 = __float_as_int(__shfl(srcf, i + 2));
        int   r3 = __float_as_int(__shfl(srcf, i + 3));
        float v0 = __shfl(val, i);
        float v1 = __shfl(val, i + 1);
        float v2 = __shfl(val, i + 2);
        float v3 = __shfl(val, i + 3);
        float2 f0 = h2f(xh[(size_t)r0 * 64 + lane]);
        float2 f1 = h2f(xh[(size_t)r1 * 64 + lane]);
        float2 f2 = h2f(xh[(size_t)r2 * 64 + lane]);
        float2 f3 = h2f(xh[(size_t)r3 * 64 + lane]);
        accx += v0 * f0.x + v1 * f1.x + v2 * f2.x + v3 * f3.x;
        accy += v0 * f0.y + v1 * f1.y + v2 * f2.y + v3 * f3.y;
    }
    for (; i < n; i++) {
        int   r0 = __float_as_int(__shfl(srcf, i));
        float v0 = __shfl(val, i);
        float2 f0 = h2f(xh[(size_t)r0 * 64 + lane]);
        accx += v0 * f0.x;
        accy += v0 * f0.y;
    }

    float2 b = ((const float2*)bias)[lane];
    float ox = fmaxf(dv * accx + b.x, 0.0f);
    float oy = fmaxf(dv * accy + b.y, 0.0f);
    ((unsigned int*)outh)[(size_t)node * 64 + lane] = f2h(ox, oy);
}

// ---------------------------------------------------------------------------
// Pool (fp16 in): grid = graph x slice; unroll-4 ILP; LDS reduce; atomics.
// ---------------------------------------------------------------------------
__global__ __launch_bounds__(256) void pool_kernel(const __half* __restrict__ h,
                                                   const int* __restrict__ gstart,
                                                   float* __restrict__ pooled) {
    int g = blockIdx.x >> 3;
    int s = blockIdx.x & (POOL_SPLIT - 1);
    int a = gstart[g], b = gstart[g + 1];
    int len = b - a;
    int lo = a + (int)((long long)len * s / POOL_SPLIT);
    int hi = a + (int)((long long)len * (s + 1) / POOL_SPLIT);

    int d2 = threadIdx.x & 63;
    int nl = threadIdx.x >> 6;
    const unsigned int* h2 = (const unsigned int*)h;

    float accx = 0.0f, accy = 0.0f;
    int n = lo + nl;
    for (; n + 12 < hi; n += 16) {
        float2 v0 = h2f(h2[(size_t)n * 64 + d2]);
        float2 v1 = h2f(h2[(size_t)(n + 4) * 64 + d2]);
        float2 v2 = h2f(h2[(size_t)(n + 8) * 64 + d2]);
        float2 v3 = h2f(h2[(size_t)(n + 12) * 64 + d2]);
        accx += (v0.x + v1.x) + (v2.x + v3.x);
        accy += (v0.y + v1.y) + (v2.y + v3.y);
    }
    for (; n < hi; n += 4) {
        float2 v = h2f(h2[(size_t)n * 64 + d2]);
        accx += v.x; accy += v.y;
    }

    __shared__ float red[4][128];
    red[nl][d2 * 2]     = accx;
    red[nl][d2 * 2 + 1] = accy;
    __syncthreads();
    if (threadIdx.x < 128) {
        float v = red[0][threadIdx.x] + red[1][threadIdx.x]
                + red[2][threadIdx.x] + red[3][threadIdx.x];
        atomicAdd(&pooled[(size_t)g * 128 + threadIdx.x], v);
    }
}

__global__ __launch_bounds__(64) void final_kernel(const float* __restrict__ pooled,
                                                   const int* __restrict__ gstart,
                                                   const float* __restrict__ Wh,
                                                   const float* __restrict__ bh,
                                                   float* __restrict__ out) {
    int g = blockIdx.x;
    int t = threadIdx.x;
    float v = pooled[(size_t)g * 128 + t] * Wh[t]
            + pooled[(size_t)g * 128 + 64 + t] * Wh[64 + t];
#pragma unroll
    for (int off = 32; off > 0; off >>= 1) v += __shfl_down(v, off, 64);
    if (t == 0) {
        float cntf = (float)(gstart[g + 1] - gstart[g]);
        out[g] = v / fmaxf(cntf, 1.0f) + bh[0];
    }
}

// ---------------------------------------------------------------------------
extern "C" void kernel_launch(void* const* d_in, const int* in_sizes, int n_in,
                              void* d_out, int out_size, void* d_ws, size_t ws_size,
                              hipStream_t stream) {
    const float* x   = (const float*)d_in[0];
    const float* ew  = (const float*)d_in[1];
    const float* W1  = (const float*)d_in[2];
    const float* b1  = (const float*)d_in[3];
    const float* W2  = (const float*)d_in[4];
    const float* b2  = (const float*)d_in[5];
    const float* Wh  = (const float*)d_in[6];
    const float* bh  = (const float*)d_in[7];
    const int*   ei  = (const int*)d_in[8];
    const int*   bat = (const int*)d_in[9];
    float* out = (float*)d_out;

    char* ws = (char*)d_ws;
    __half* bufAh  = (__half*)ws;                         ws += (size_t)N_NODES * D * 2;
    __half* bufBh  = (__half*)ws;                         ws += (size_t)N_NODES * D * 2;
    float2* bucket = (float2*)ws;                         ws += (size_t)N_NODES * CAP * 8;
    unsigned long long* packed = (unsigned long long*)ws; ws += (size_t)N_NODES * 8;
    float*  dinv   = (float*)ws;                          ws += (size_t)N_NODES * 4;
    int*    cnt    = (int*)ws;                            ws += (size_t)N_NODES * 4;
    int*    gstart = (int*)ws;                            ws += (N_GRAPHS + 1) * 4;
    float*  pooled = (float*)ws;                          ws += (size_t)N_GRAPHS * D * 4;

    const int nb_nodes = (N_NODES + 255) / 256;       // 196
    const int nb_gemm  = (N_NODES + 127) / 128;       // 391
    const int nb_agg   = N_NODES / 4;                 // 12500 (exact)
    const int nb_scale = N_NODES * 64 / 256;          // 12500 (exact)
    const int nb_pool  = N_GRAPHS * POOL_SPLIT;       // 512

    // --- zero counters/pool (memset replaces init kernel) ---
    hipMemsetAsync(packed, 0, (size_t)N_NODES * 8, stream);
    hipMemsetAsync(pooled, 0, (size_t)N_GRAPHS * D * 4, stream);

    // --- fused: gemm1 (x@W1 -> fp16) overlapped with fill (atomic-bound) ---
    fused_gemm1_fill<<<NB_GEMM1 + NB_FILL, 256, 0, stream>>>(x, W1, bufAh, ei, ew, packed, bucket);
    dinv_gstart_kernel<<<nb_nodes, 256, 0, stream>>>(packed, cnt, dinv, bat, gstart);
    scale_kernel<<<nb_scale, 256, 0, stream>>>((unsigned int*)bufAh, dinv);

    // --- layer 1 agg ---
    agg_bucket_kernel<<<nb_agg, 256, 0, stream>>>(bufAh, cnt, bucket, dinv, b1, bufBh);

    // --- layer 2 ---
    gemm128h2<<<nb_gemm, 256, 0, stream>>>(bufBh, W2, dinv, bufAh);
    agg_bucket_kernel<<<nb_agg, 256, 0, stream>>>(bufAh, cnt, bucket, dinv, b2, bufBh);

    // --- pool + head ---
    pool_kernel<<<nb_pool, 256, 0, stream>>>(bufBh, gstart, pooled);
    final_kernel<<<N_GRAPHS, 64, 0, stream>>>(pooled, gstart, Wh, bh, out);
}